// Round 9
// baseline (66.603 us; speedup 1.0000x reference)
//
#include <hip/hip_runtime.h>

// Problem constants
#define NN 20000
#define SS 400
#define QP 60                      // floats per (q,p) row
#define NPAIRS 10000               // n-pairs
#define JPB 64                     // n-pairs per block (one per lane)
#define NBLK ((NPAIRS + JPB - 1)/JPB)  // 157
#define JPAD (NBLK*JPB)            // 10048
#define NP2 (JPAD*2)               // 20096 padded n
#define GSPLIT 5                   // s chunks across gridDim.y
#define SB (SS/GSPLIT)             // 80 s per block
#define WAVES 8
#define BLK_B (WAVES*64)           // 512
#define SW (SB/WAVES)              // 10 s per wave
#define PTF4 (JPB*30)              // 1920 float4 per block's pauli tile
#define PF4TOT (NN*QP/4)           // 300000 float4 in pauli

// ws layout (floats)
#define WS_H    0                            // heads2 r2-folded [400][60]
#define WS_PT   (SS*QP)                      // 24000: block-transposed pauli [NBLK][30][64] float4
#define WS_COV  (WS_PT + NBLK*PTF4*4)        // partial coverage [GSPLIT][NP2]
#define WS_CNT  (WS_COV + GSPLIT*NP2)        // per-bx arrival counters (int)

typedef float v2f __attribute__((ext_vector_type(2)));

__device__ __forceinline__ v2f lo4(float4 f) { v2f r; r.x = f.x; r.y = f.y; return r; }
__device__ __forceinline__ v2f hi4(float4 f) { v2f r; r.x = f.z; r.y = f.w; return r; }

// prep: 157 blocks x 512. Coalesced LDS-based pauli pair-transpose +
// heads/ratios echo outputs + r2-folded heads table + zero out[0] & counters.
__global__ __launch_bounds__(512) void prep_kernel(
        const float* __restrict__ heads_param,
        const float* __restrict__ ratios_param,
        const float* __restrict__ pauli,
        float* __restrict__ out, float* __restrict__ ws) {
    __shared__ float ldsR[JPB*2*QP];   // 128 rows x 60 floats = 30 KB

    const int tid = threadIdx.x;
    const int bx  = blockIdx.x;

    // 1) Linear, fully-coalesced load of this block's 128 pauli rows
    {
        const float4* src = reinterpret_cast<const float4*>(pauli) + (size_t)bx * PTF4;
        float4* dst = reinterpret_cast<float4*>(ldsR);
        #pragma unroll
        for (int it = 0; it < 4; ++it) {
            int i = tid + it*512;
            if (i < PTF4) {
                int gi = bx*PTF4 + i;
                dst[i] = (gi < PF4TOT) ? src[i] : make_float4(0.f,0.f,0.f,0.f);
            }
        }
    }
    __syncthreads();

    // 2) Pair-interleaved PT tile, coalesced global writes
    {
        float4* pt = reinterpret_cast<float4*>(ws + WS_PT) + (size_t)bx * PTF4;
        #pragma unroll
        for (int it = 0; it < 4; ++it) {
            int i = tid + it*512;
            if (i < PTF4) {
                int k = i >> 6, l = i & 63;
                float4 v;
                v.x = ldsR[(2*l  )*QP + 2*k    ];
                v.y = ldsR[(2*l+1)*QP + 2*k    ];
                v.z = ldsR[(2*l  )*QP + 2*k + 1];
                v.w = ldsR[(2*l+1)*QP + 2*k + 1];
                pt[i] = v;
            }
        }
    }

    // 3) heads / ratios outputs + r2-folded heads table + zero loss & counters
    const int gi = bx*512 + tid;
    if (gi < SS*QP) {
        int s = gi / QP;
        float h = heads_param[gi];
        float h2 = h * h;
        out[1 + SS + gi] = h2;                         // heads output (unscaled)
        float rr = ratios_param[s];
        ws[WS_H + gi] = ((gi - s*QP) < 3) ? h2 * (rr*rr) : h2;  // fold r2 into q=0 dot
    }
    if (gi < SS) {
        float rr = ratios_param[gi];
        out[1 + gi] = rr * rr;                         // ratios output
    }
    if (gi == 0) out[0] = 0.f;                         // atomic accumulator base
    if (gi < NBLK) reinterpret_cast<int*>(ws + WS_CNT)[gi] = 0;  // split-K counters
}

// One s-step for q-chunk c: 3 wave-uniform (s_load) reads of heads chunk,
// 15 packed ops covering (1 s, 4 q, 2 n).
#define S_STEP(A, SI)                                                   \
    do {                                                                \
        const float4* hf = reinterpret_cast<const float4*>(hrow + (SI)*QP + c*12); \
        float4 f0 = hf[0], f1 = hf[1], f2 = hf[2];                      \
        v2f d0 = pq0*f0.x + pq1*f0.y  + pq2*f0.z;                       \
        v2f d1 = pq3*f0.w + pq4*f1.x  + pq5*f1.y;                       \
        v2f d2 = pq6*f1.z + pq7*f1.w  + pq8*f2.x;                       \
        v2f d3 = pq9*f2.y + pq10*f2.z + pq11*f2.w;                      \
        A *= (d0*d1)*(d2*d3);                                           \
    } while (0)

__global__ __launch_bounds__(BLK_B) void main_kernel(
        const float* __restrict__ hws,   // ws + WS_H  (read-only, disjoint)
        const float4* __restrict__ pt,   // ws + WS_PT (read-only, disjoint)
        float* cov,                      // ws + WS_COV (write partials, finalize reads)
        int*   cnt,                      // ws + WS_CNT per-bx arrival counters
        const float* __restrict__ coeff,
        float* out) {
    __shared__ float4 ldsP[PTF4];        // 30 KB block-transposed pauli tile
    __shared__ v2f    ldsC[WAVES][64];   // 4 KB cross-wave reduce
    __shared__ float  red[2];
    __shared__ int    isLast;

    const int tid  = threadIdx.x;
    const int wave = __builtin_amdgcn_readfirstlane(tid >> 6);
    const int lane = tid & 63;
    const int g    = blockIdx.y;
    const int bx   = blockIdx.x;

    // Stage this block's pauli tile: linear copy, coalesced + conflict-free
    {
        const float4* src = pt + (size_t)bx * PTF4;
        for (int i = tid; i < PTF4; i += BLK_B) ldsP[i] = src[i];
    }
    __syncthreads();

    // This wave's 10 heads rows (wave-uniform address -> scalar loads)
    const float* hrow = hws + (size_t)(g*SB + wave*SW) * QP;

    v2f one; one.x = 1.f; one.y = 1.f;
    v2f a0=one,a1=one,a2=one,a3=one,a4=one,a5=one,a6=one,a7=one,a8=one,a9=one;

    #pragma unroll 1    // q-phase split: 24 pauli floats live at a time
    for (int c = 0; c < 5; ++c) {
        float4 q0 = ldsP[(c*6+0)*64+lane], q1 = ldsP[(c*6+1)*64+lane];
        float4 q2 = ldsP[(c*6+2)*64+lane], q3 = ldsP[(c*6+3)*64+lane];
        float4 q4 = ldsP[(c*6+4)*64+lane], q5 = ldsP[(c*6+5)*64+lane];
        v2f pq0 = lo4(q0), pq1  = hi4(q0), pq2  = lo4(q1), pq3  = hi4(q1);
        v2f pq4 = lo4(q2), pq5  = hi4(q2), pq6  = lo4(q3), pq7  = hi4(q3);
        v2f pq8 = lo4(q4), pq9  = hi4(q4), pq10 = lo4(q5), pq11 = hi4(q5);
        S_STEP(a0, 0); S_STEP(a1, 1); S_STEP(a2, 2); S_STEP(a3, 3); S_STEP(a4, 4);
        S_STEP(a5, 5); S_STEP(a6, 6); S_STEP(a7, 7); S_STEP(a8, 8); S_STEP(a9, 9);
    }

    // Sum over this wave's s (r2 already folded in)
    v2f cv = (((a0+a1)+(a2+a3)) + ((a4+a5)+(a6+a7))) + (a8+a9);
    ldsC[wave][lane] = cv;
    __syncthreads();

    if (wave == 0) {
        v2f t = ldsC[0][lane];
        #pragma unroll
        for (int w = 1; w < WAVES; ++w) t += ldsC[w][lane];
        const int j = bx * JPB + lane;
        *reinterpret_cast<v2f*>(cov + (size_t)g * NP2 + 2*j) = t;
        __threadfence();                       // release: cov partial visible device-wide
        if (lane == 0) {
            int old = atomicAdd(cnt + bx, 1);  // device-scope arrival
            isLast = (old == GSPLIT - 1);
        }
    }
    __syncthreads();

    // Last-arriving g-block for this bx finalizes its 128 n's
    if (isLast) {
        __threadfence();                       // acquire: see all g partials
        if (tid < 2*JPB) {
            const int n = bx * (2*JPB) + tid;
            float term = 0.f;
            if (n < NN) {
                float cs = 0.f;
                #pragma unroll
                for (int g2 = 0; g2 < GSPLIT; ++g2) cs += cov[(size_t)g2 * NP2 + n];
                float c = coeff[n];
                term = (c * c) / cs;
            }
            #pragma unroll
            for (int off = 32; off; off >>= 1) term += __shfl_down(term, off);
            if ((tid & 63) == 0) red[tid >> 6] = term;
        }
        __syncthreads();
        if (tid == 0) atomicAdd(out, red[0] + red[1]);
    }
}

extern "C" void kernel_launch(void* const* d_in, const int* in_sizes, int n_in,
                              void* d_out, int out_size, void* d_ws, size_t ws_size,
                              hipStream_t stream) {
    const float* heads_param  = (const float*)d_in[0];   // [S,Q,P]
    const float* ratios_param = (const float*)d_in[1];   // [S]
    const float* pauli        = (const float*)d_in[2];   // [N,Q,P]
    const float* coeff        = (const float*)d_in[3];   // [N]
    float* out = (float*)d_out;
    float* ws  = (float*)d_ws;

    prep_kernel<<<NBLK, 512, 0, stream>>>(heads_param, ratios_param, pauli, out, ws);
    main_kernel<<<dim3(NBLK, GSPLIT), BLK_B, 0, stream>>>(
        ws + WS_H, (const float4*)(ws + WS_PT), ws + WS_COV,
        (int*)(ws + WS_CNT), coeff, out);
}

// Round 10
// 32.625 us; speedup vs baseline: 2.0415x; 2.0415x over previous
//
#include <hip/hip_runtime.h>

// Problem constants
#define NN 20000
#define SS 400
#define QP 60                      // floats per (q,p) row
#define NPAIRS 10000               // n-pairs
#define JPB 64                     // n-pairs per block (one per lane)
#define NBLK ((NPAIRS + JPB - 1)/JPB)  // 157
#define JPAD (NBLK*JPB)            // 10048
#define NP2 (JPAD*2)               // 20096 padded n
#define GSPLIT 5                   // s chunks across gridDim.y
#define SB (SS/GSPLIT)             // 80 s per block
#define WAVES 8
#define BLK_B (WAVES*64)           // 512
#define SW (SB/WAVES)              // 10 s per wave
#define NC 5                       // q-chunks (4 qubits / 12 floats each)
#define PTF4 (JPB*30)              // 1920 float4 per block's pauli tile
#define PF4TOT (NN*QP/4)           // 300000 float4 in pauli

// ws layout (floats)
#define WS_H    0                            // heads2 r2-folded, c-major [GSPLIT][NC][SB][12]
#define WS_PT   (SS*QP)                      // 24000: block-transposed pauli [NBLK][30][64] float4
#define WS_COV  (WS_PT + NBLK*PTF4*4)        // partial coverage [GSPLIT][NP2]
#define CBLK    ((NP2 + 255)/256)            // 79 combine blocks

typedef float v2f __attribute__((ext_vector_type(2)));

__device__ __forceinline__ v2f lo4(float4 f) { v2f r; r.x = f.x; r.y = f.y; return r; }
__device__ __forceinline__ v2f hi4(float4 f) { v2f r; r.x = f.z; r.y = f.w; return r; }

// prep: 157 blocks x 512. Coalesced LDS-based pauli pair-transpose +
// heads/ratios echo outputs + c-major r2-folded heads table + out[0]=0.
__global__ __launch_bounds__(512) void prep_kernel(
        const float* __restrict__ heads_param,
        const float* __restrict__ ratios_param,
        const float* __restrict__ pauli,
        float* __restrict__ out, float* __restrict__ ws) {
    __shared__ float ldsR[JPB*2*QP];   // 128 rows x 60 floats = 30 KB

    const int tid = threadIdx.x;
    const int bx  = blockIdx.x;

    // 1) Linear, fully-coalesced load of this block's 128 pauli rows
    {
        const float4* src = reinterpret_cast<const float4*>(pauli) + (size_t)bx * PTF4;
        float4* dst = reinterpret_cast<float4*>(ldsR);
        #pragma unroll
        for (int it = 0; it < 4; ++it) {
            int i = tid + it*512;
            if (i < PTF4) {
                int gi = bx*PTF4 + i;
                dst[i] = (gi < PF4TOT) ? src[i] : make_float4(0.f,0.f,0.f,0.f);
            }
        }
    }
    __syncthreads();

    // 2) Pair-interleaved PT tile, coalesced global writes
    {
        float4* pt = reinterpret_cast<float4*>(ws + WS_PT) + (size_t)bx * PTF4;
        #pragma unroll
        for (int it = 0; it < 4; ++it) {
            int i = tid + it*512;
            if (i < PTF4) {
                int k = i >> 6, l = i & 63;
                float4 v;
                v.x = ldsR[(2*l  )*QP + 2*k    ];
                v.y = ldsR[(2*l+1)*QP + 2*k    ];
                v.z = ldsR[(2*l  )*QP + 2*k + 1];
                v.w = ldsR[(2*l+1)*QP + 2*k + 1];
                pt[i] = v;
            }
        }
    }

    // 3) heads / ratios outputs + c-major r2-folded heads table + zero loss
    const int gi = bx*512 + tid;
    if (gi < SS*QP) {
        int s = gi / QP;
        int k = gi - s*QP;
        float h = heads_param[gi];
        float h2 = h * h;
        out[1 + SS + gi] = h2;                         // heads output (unscaled)
        float rr = ratios_param[s];
        float v = (k < 3) ? h2 * (rr*rr) : h2;         // fold r2 into q=0 dot
        int g  = s / SB, sl = s - g*SB;
        int c  = k / 12, kk = k - c*12;
        // c-major: per (g,c) the 80x12 block is contiguous (sL1-resident)
        ws[WS_H + (((size_t)g*NC + c)*SB + sl)*12 + kk] = v;
    }
    if (gi < SS) {
        float rr = ratios_param[gi];
        out[1 + gi] = rr * rr;                         // ratios output
    }
    if (gi == 0) out[0] = 0.f;                         // atomic accumulator base
}

// One s-step for q-chunk c: 3 wave-uniform scalar reads (contiguous within
// the c-chunk), 15 packed ops covering (1 s, 4 q, 2 n).
#define S_STEP(A, SI)                                                   \
    do {                                                                \
        const float4* hf = reinterpret_cast<const float4*>(hc + (SI)*12); \
        float4 f0 = hf[0], f1 = hf[1], f2 = hf[2];                      \
        v2f d0 = pq0*f0.x + pq1*f0.y  + pq2*f0.z;                       \
        v2f d1 = pq3*f0.w + pq4*f1.x  + pq5*f1.y;                       \
        v2f d2 = pq6*f1.z + pq7*f1.w  + pq8*f2.x;                       \
        v2f d3 = pq9*f2.y + pq10*f2.z + pq11*f2.w;                      \
        A *= (d0*d1)*(d2*d3);                                           \
    } while (0)

__global__ __launch_bounds__(BLK_B) void main_kernel(
        const float* __restrict__ hws,   // ws + WS_H  (read-only, disjoint)
        const float4* __restrict__ pt,   // ws + WS_PT (read-only, disjoint)
        float* __restrict__ cov) {       // ws + WS_COV (write)
    __shared__ float4 ldsP[PTF4];        // 30 KB block-transposed pauli tile
    __shared__ v2f    ldsC[WAVES][64];   // 4 KB cross-wave reduce

    const int tid  = threadIdx.x;
    const int wave = __builtin_amdgcn_readfirstlane(tid >> 6);
    const int lane = tid & 63;
    const int g    = blockIdx.y;
    const int bx   = blockIdx.x;

    // Stage this block's pauli tile: linear copy, coalesced + conflict-free
    {
        const float4* src = pt + (size_t)bx * PTF4;
        for (int i = tid; i < PTF4; i += BLK_B) ldsP[i] = src[i];
    }
    __syncthreads();

    v2f one; one.x = 1.f; one.y = 1.f;
    v2f a0=one,a1=one,a2=one,a3=one,a4=one,a5=one,a6=one,a7=one,a8=one,a9=one;

    #pragma unroll 1    // q-phase split: 24 pauli floats live at a time
    for (int c = 0; c < NC; ++c) {
        // this wave's 10 s-rows for chunk c: 120 CONTIGUOUS floats (480 B)
        const float* hc = hws + (((size_t)g*NC + c)*SB + wave*SW)*12;
        float4 q0 = ldsP[(c*6+0)*64+lane], q1 = ldsP[(c*6+1)*64+lane];
        float4 q2 = ldsP[(c*6+2)*64+lane], q3 = ldsP[(c*6+3)*64+lane];
        float4 q4 = ldsP[(c*6+4)*64+lane], q5 = ldsP[(c*6+5)*64+lane];
        v2f pq0 = lo4(q0), pq1  = hi4(q0), pq2  = lo4(q1), pq3  = hi4(q1);
        v2f pq4 = lo4(q2), pq5  = hi4(q2), pq6  = lo4(q3), pq7  = hi4(q3);
        v2f pq8 = lo4(q4), pq9  = hi4(q4), pq10 = lo4(q5), pq11 = hi4(q5);
        S_STEP(a0, 0); S_STEP(a1, 1); S_STEP(a2, 2); S_STEP(a3, 3); S_STEP(a4, 4);
        S_STEP(a5, 5); S_STEP(a6, 6); S_STEP(a7, 7); S_STEP(a8, 8); S_STEP(a9, 9);
    }

    // Sum over this wave's s (r2 already folded in)
    v2f cv = (((a0+a1)+(a2+a3)) + ((a4+a5)+(a6+a7))) + (a8+a9);
    ldsC[wave][lane] = cv;
    __syncthreads();

    if (wave == 0) {
        v2f t = ldsC[0][lane];
        #pragma unroll
        for (int w = 1; w < WAVES; ++w) t += ldsC[w][lane];
        const int j = bx * JPB + lane;
        *reinterpret_cast<v2f*>(cov + (size_t)g * NP2 + 2*j) = t;
    }
}

// combine: sums the GSPLIT cov partials, computes c^2/cov, block-reduces,
// one atomicAdd per block into out[0] (zeroed by prep earlier in-stream).
__global__ void combine_kernel(const float* __restrict__ ws,
                               const float* __restrict__ coeff,
                               float* __restrict__ out) {
    __shared__ float red[4];
    const int tid = threadIdx.x;
    const int n = blockIdx.x * 256 + tid;
    float term = 0.f;
    if (n < NN) {
        float cov = 0.f;
        #pragma unroll
        for (int g = 0; g < GSPLIT; ++g) cov += ws[WS_COV + (size_t)g * NP2 + n];
        float c = coeff[n];
        term = (c * c) / cov;
    }
    #pragma unroll
    for (int off = 32; off; off >>= 1) term += __shfl_down(term, off);
    if ((tid & 63) == 0) red[tid >> 6] = term;
    __syncthreads();
    if (tid == 0) atomicAdd(out, red[0] + red[1] + red[2] + red[3]);
}

extern "C" void kernel_launch(void* const* d_in, const int* in_sizes, int n_in,
                              void* d_out, int out_size, void* d_ws, size_t ws_size,
                              hipStream_t stream) {
    const float* heads_param  = (const float*)d_in[0];   // [S,Q,P]
    const float* ratios_param = (const float*)d_in[1];   // [S]
    const float* pauli        = (const float*)d_in[2];   // [N,Q,P]
    const float* coeff        = (const float*)d_in[3];   // [N]
    float* out = (float*)d_out;
    float* ws  = (float*)d_ws;

    prep_kernel<<<NBLK, 512, 0, stream>>>(heads_param, ratios_param, pauli, out, ws);
    main_kernel<<<dim3(NBLK, GSPLIT), BLK_B, 0, stream>>>(
        ws + WS_H, (const float4*)(ws + WS_PT), ws + WS_COV);
    combine_kernel<<<CBLK, 256, 0, stream>>>(ws, coeff, out);
}